// Round 1
// 514.828 us; speedup vs baseline: 1.0621x; 1.0621x over previous
//
#include <hip/hip_runtime.h>

// ---------------- problem constants ----------------
#define NN 50000
#define EE 800000
// HID=128, EDGE_DIM=16, HEADS=4, C=32

typedef unsigned short u16;

// ---------------- ws layout (4-byte element offsets), total ~64.3 MB ----------------
// Region A: gat (live k2..k5)
#define OFF_GAT  0u          // N*128 f32 = 6,400,000 slots
// Region B: k1/k2 operands; dead after k2 -> h aliases XLB+XRB exactly
#define OFF_XLB  6400000u    // N*128 bf16 = 3,200,000 f32 slots -> 6.4M..9.6M
#define OFF_XRB  9600000u    // N*128 bf16 = 3,200,000 f32 slots -> 9.6M..12.8M
#define OFF_SE   12800000u   // E int2 (CSR-ordered {src, eid})  -> 12.8M..14.4M
#define OFF_CNT  14400000u   // N ints (hist; then CSR cursors)  -> 14.4M..14.45M
#define OFF_OFS  14450000u   // N+1 ints
#define OFF_H    6400000u    // N*128 f32, aliases XLB+XRB (6.4M..12.8M), after k2
#define OFF_HB   12800000u   // N*128 bf16, aliases SE+CNT+OFS (12.8M..16M), after k2
// Region C: weights (live to the end), 16B-aligned offsets
#define OFF_WLRT 16000000u   // 256x128 bf16 = 16,384 f32 slots
#define OFF_W1T  16016384u   // 512x128 bf16 = 32,768 f32 slots
#define OFF_W2T  16049152u   // 128x512 bf16 = 32,768 f32 slots
// end: 16,081,920 f32 = 64,327,680 bytes (< proven 67.9 MB budget)

#define RMS_EPS 1.1920928955078125e-7f

typedef float f32x4v __attribute__((ext_vector_type(4)));
typedef short s16x8 __attribute__((ext_vector_type(8)));

__device__ __forceinline__ f32x4v mfma16(s16x8 a, s16x8 b, f32x4v c) {
  return __builtin_amdgcn_mfma_f32_16x16x32_bf16(a, b, c, 0, 0, 0);
}
__device__ __forceinline__ u16 f2b(float f) {
  unsigned int u = __float_as_uint(f);
  unsigned int r = (u + 0x7fffu + ((u >> 16) & 1u)) >> 16;
  return (u16)r;
}
__device__ __forceinline__ float b2f(u16 u) {
  union { float f; unsigned int i; } x; x.i = ((unsigned int)u) << 16; return x.f;
}
// load 8 fp32, convert to bf16 fragment in-register
__device__ __forceinline__ s16x8 ld_bf16x8_f32(const float* __restrict__ p) {
  float4 v0 = *(const float4*)p;
  float4 v1 = *(const float4*)(p + 4);
  s16x8 r;
  r[0] = (short)f2b(v0.x); r[1] = (short)f2b(v0.y);
  r[2] = (short)f2b(v0.z); r[3] = (short)f2b(v0.w);
  r[4] = (short)f2b(v1.x); r[5] = (short)f2b(v1.y);
  r[6] = (short)f2b(v1.z); r[7] = (short)f2b(v1.w);
  return r;
}
__device__ __forceinline__ float readlane_f32(float v, int lane) {
  return __int_as_float(__builtin_amdgcn_readlane(__float_as_int(v), lane));
}
__device__ __forceinline__ int readlane_i32(int v, int lane) {
  return __builtin_amdgcn_readlane(v, lane);
}
// tanh-form GELU via sigmoid: x*sigmoid(1.5957691*x + 0.0713548*x^3)
// max |err| vs exact erf GELU ~2e-4 -- far below bf16 rounding of f (4e-3)
__device__ __forceinline__ float gelu_fast(float x) {
  float x2 = x * x;
  float y = x * fmaf(0.07135481283f, x2, 1.5957691216f);
  float e = __expf(-y);
  return x * __builtin_amdgcn_rcpf(1.0f + e);
}

// ---------------- fused prep: zero hist + 3 weight transposes (bf16) ----------------
__global__ __launch_bounds__(256) void k_prep(const float* __restrict__ Wl, const float* __restrict__ Wr,
    const float* __restrict__ W1, const float* __restrict__ W2,
    int* __restrict__ cnt, u16* __restrict__ wlrt, u16* __restrict__ w1t, u16* __restrict__ w2t)
{
  int i = blockIdx.x * 256 + threadIdx.x;   // 65536 threads
  if (i < NN) cnt[i] = 0;
  if (i < 32768) {
    int n = i >> 7, k = i & 127;
    float v = (n < 128) ? Wl[k * 128 + n] : Wr[k * 128 + (n - 128)];
    wlrt[i] = f2b(v);
  }
  {
    int n = i >> 7, k = i & 127;
    w1t[i] = f2b(W1[k * 512 + n]);
  }
  {
    int n = i >> 9, k = i & 511;
    w2t[i] = f2b(W2[k * 128 + n]);
  }
}

// ---------------- CSR build ----------------
__global__ __launch_bounds__(256) void k_hist(const int* __restrict__ ei, int* __restrict__ cnt) {
  int e = blockIdx.x * 256 + threadIdx.x;
  if (e < EE) atomicAdd(&cnt[ei[EE + e]], 1);
}

// scan: offs = exclusive prefix (N+1); pos (aliases cnt, in-place) = cursors
__global__ __launch_bounds__(1024) void k_scan(const int* __restrict__ cnt,
    int* __restrict__ offs, int* __restrict__ pos)
{
  __shared__ int wsum[16];
  __shared__ int carry_s;
  int tid = threadIdx.x, lane = tid & 63, wv = tid >> 6;
  if (tid == 0) carry_s = 0;
  __syncthreads();
  for (int base = 0; base < NN; base += 1024) {
    int i = base + tid;
    int v = (i < NN) ? cnt[i] : 0;
    int x = v;
#pragma unroll
    for (int ofs = 1; ofs < 64; ofs <<= 1) {
      int y = __shfl_up(x, ofs);
      if (lane >= ofs) x += y;
    }
    if (lane == 63) wsum[wv] = x;
    __syncthreads();
    if (wv == 0) {
      int s = (lane < 16) ? wsum[lane] : 0;
#pragma unroll
      for (int ofs = 1; ofs < 16; ofs <<= 1) {
        int y = __shfl_up(s, ofs);
        if (lane >= ofs) s += y;
      }
      if (lane < 16) wsum[lane] = s;
    }
    __syncthreads();
    int wbase = (wv > 0) ? wsum[wv - 1] : 0;
    int incl = x + wbase + carry_s;
    if (i < NN) { offs[i + 1] = incl; pos[i] = incl - v; }
    if (base == 0 && tid == 0) offs[0] = 0;
    __syncthreads();
    if (tid == 1023) carry_s = incl;
    __syncthreads();
  }
}

// permute: CSR-ordered {src, eid} packed, one 8B store per edge
__global__ __launch_bounds__(256) void k_permute(const int* __restrict__ ei,
    int* __restrict__ pos, int2* __restrict__ se)
{
  int e = blockIdx.x * 256 + threadIdx.x;
  if (e < EE) {
    int slot = atomicAdd(&pos[ei[EE + e]], 1);
    se[slot] = make_int2(ei[e], e);
  }
}

// ---------------- K1: [xl|xr] = x @ [Wl|Wr] + [bl|br] -> bf16 ----------------
__global__ __launch_bounds__(256) void k1_mfma(const float* __restrict__ x, const u16* __restrict__ wlrt,
    const float* __restrict__ bl, const float* __restrict__ br,
    u16* __restrict__ xlb, u16* __restrict__ xrb)
{
  int tid = threadIdx.x;
  int w = tid >> 6, lane = tid & 63;
  int quad = lane >> 4, l16 = lane & 15;
  int row0 = blockIdx.x * 32;
  int ko = quad * 8;
  f32x4v acc[2][4];
#pragma unroll
  for (int mt = 0; mt < 2; ++mt)
#pragma unroll
    for (int nt = 0; nt < 4; ++nt) acc[mt][nt] = (f32x4v){0.f, 0.f, 0.f, 0.f};
#pragma unroll
  for (int ks = 0; ks < 4; ++ks) {
    int k0 = ks * 32 + ko;
    s16x8 a[2];
#pragma unroll
    for (int mt = 0; mt < 2; ++mt) {
      int row = row0 + mt * 16 + l16; if (row >= NN) row = NN - 1;
      a[mt] = ld_bf16x8_f32(x + row * 128 + k0);
    }
#pragma unroll
    for (int nt = 0; nt < 4; ++nt) {
      int col = w * 64 + nt * 16 + l16;
      s16x8 b = *(const s16x8*)(wlrt + col * 128 + k0);
      acc[0][nt] = mfma16(a[0], b, acc[0][nt]);
      acc[1][nt] = mfma16(a[1], b, acc[1][nt]);
    }
  }
#pragma unroll
  for (int nt = 0; nt < 4; ++nt) {
    int col = w * 64 + nt * 16 + l16;
    bool isl = col < 128;
    float bias = isl ? bl[col] : br[col - 128];
    u16* dst = isl ? xlb : xrb;
    int cc = isl ? col : col - 128;
#pragma unroll
    for (int mt = 0; mt < 2; ++mt)
#pragma unroll
      for (int r = 0; r < 4; ++r) {
        int row = row0 + mt * 16 + quad * 4 + r;
        if (row < NN) dst[row * 128 + cc] = f2b(acc[mt][nt][r] + bias);
      }
  }
}

// ---------------- K2: fused logits + 4-edge-batched online softmax (wave/dst) ----------------
__global__ __launch_bounds__(256) void k2_attn(
    const int* __restrict__ offs, const int2* __restrict__ se,
    const float* __restrict__ eattr,
    const float* __restrict__ att, const float* __restrict__ We,
    const u16* __restrict__ xlb, const u16* __restrict__ xrb,
    float* __restrict__ gat)
{
  int l = threadIdx.x & 63;
  int wid = (blockIdx.x * blockDim.x + threadIdx.x) >> 6;
  int nw = (gridDim.x * blockDim.x) >> 6;
  int c0 = 2 * l;
  const float2* We2 = (const float2*)We;   // [16][64] float2: cols 2l,2l+1
  float2 wef[16];
#pragma unroll
  for (int k = 0; k < 16; ++k) wef[k] = We2[k * 64 + l];
  float a0 = att[c0], a1 = att[c0 + 1];
  for (int d = wid; d < NN; d += nw) {
    int start = offs[d];
    int deg = offs[d + 1] - start;
    ushort2 xru = *(const ushort2*)(xrb + d * 128 + c0);
    float xr0 = b2f(xru.x), xr1 = b2f(xru.y);
    float mh = -1e30f, lh = 0.f, O0 = 0.f, O1 = 0.f;
    for (int base = 0; base < deg; base += 64) {
      bool act = (base + l) < deg;
      int idx = start + base + l;
      int2 sev = act ? se[idx] : make_int2(0, 0);
      int cnt = min(64, deg - base);
      for (int sub = 0; sub < cnt; sub += 4) {
        // eattr rows for 4 edges: lane covers edge (l>>4), dim (l&15)
        int eidq = __shfl(sev.y, sub + (l >> 4));
        float eav = eattr[eidq * 16 + (l & 15)];
        float p[4], xl0v[4], xl1v[4];
#pragma unroll
        for (int j2 = 0; j2 < 4; ++j2) {
          float ep0 = 0.f, ep1 = 0.f;
#pragma unroll
          for (int k = 0; k < 16; ++k) {
            float ek = readlane_f32(eav, j2 * 16 + k);
            ep0 = fmaf(ek, wef[k].x, ep0);
            ep1 = fmaf(ek, wef[k].y, ep1);
          }
          int sr = readlane_i32(sev.x, sub + j2);   // inactive lanes hold 0 -> safe row
          ushort2 xlu = *(const ushort2*)(xlb + sr * 128 + c0);
          float xl0 = b2f(xlu.x), xl1 = b2f(xlu.y);
          float m0 = xl0 + xr0 + ep0;
          float m1 = xl1 + xr1 + ep1;
          float s0 = m0 > 0.f ? m0 : 0.2f * m0;   // LeakyReLU(0.2)
          float s1 = m1 > 0.f ? m1 : 0.2f * m1;
          p[j2] = fmaf(s0, a0, s1 * a1);
          xl0v[j2] = xl0; xl1v[j2] = xl1;
        }
        // 4 interleaved reduction trees over 16-lane head groups (ILP)
#pragma unroll
        for (int o = 1; o <= 8; o <<= 1) {
          p[0] += __shfl_xor(p[0], o);
          p[1] += __shfl_xor(p[1], o);
          p[2] += __shfl_xor(p[2], o);
          p[3] += __shfl_xor(p[3], o);
        }
        // mask tail edges AFTER reduction (exp -> 0, garbage*0 = 0, no NaN)
#pragma unroll
        for (int j2 = 0; j2 < 4; ++j2) if (sub + j2 >= cnt) p[j2] = -1e30f;
        // single batched online update for 4 edges
        float nm = fmaxf(fmaxf(fmaxf(p[0], p[1]), fmaxf(p[2], p[3])), mh);
        float sc = __expf(mh - nm);
        float w0 = __expf(p[0] - nm), w1 = __expf(p[1] - nm);
        float w2 = __expf(p[2] - nm), w3 = __expf(p[3] - nm);
        lh = fmaf(lh, sc, (w0 + w1) + (w2 + w3));
        O0 = fmaf(O0, sc, fmaf(w0, xl0v[0], fmaf(w1, xl0v[1], fmaf(w2, xl0v[2], w3 * xl0v[3]))));
        O1 = fmaf(O1, sc, fmaf(w0, xl1v[0], fmaf(w1, xl1v[1], fmaf(w2, xl1v[2], w3 * xl1v[3]))));
        mh = nm;
      }
    }
    float inv = 1.f / (lh + 1e-16f);
    *(float2*)(gat + d * 128 + c0) = make_float2(O0 * inv, O1 * inv);
  }
}

// ---------------- K5: h = rmsnorm(x + gat + bias_gat, w_norm1); also emit bf16 copy ----------------
__global__ __launch_bounds__(256) void k5_norm1(const float* __restrict__ x,
    const float* __restrict__ gat, const float* __restrict__ bg,
    const float* __restrict__ wn1, float* __restrict__ h, u16* __restrict__ hb)
{
  int l = threadIdx.x & 63;
  int row = blockIdx.x * 4 + (threadIdx.x >> 6);
  int c0 = 2 * l;
  float2 xu = *(const float2*)(x + row * 128 + c0);
  float2 gv = *(const float2*)(gat + row * 128 + c0);
  float2 bu = *(const float2*)(bg + c0);
  float v0 = xu.x + gv.x + bu.x;
  float v1 = xu.y + gv.y + bu.y;
  float ss = v0 * v0 + v1 * v1;
#pragma unroll
  for (int o = 1; o < 64; o <<= 1) ss += __shfl_xor(ss, o);
  float rr = rsqrtf(ss * (1.f / 128.f) + RMS_EPS);
  float2 wu = *(const float2*)(wn1 + c0);
  float o0 = v0 * rr * wu.x, o1 = v1 * rr * wu.y;
  *(float2*)(h + row * 128 + c0) = make_float2(o0, o1);
  ushort2 hu; hu.x = f2b(o0); hu.y = f2b(o1);
  *(ushort2*)(hb + row * 128 + c0) = hu;
}

// ---------------- K6: fused FFN (bf16 MFMA) + residual + rmsnorm2 ----------------
// 512 threads / 8 waves, 32 rows per block. LDS: 32x512 bf16 = 32768 B, XOR-swizzled
// (byte ^= (row&7)<<4) -> conflict-free b128 reads at unpadded stride-1024B rows.
// rmsnorm reduction buffer aliases the (dead) tls.
__device__ __forceinline__ u16* tls_addr(u16* tls, int row, int col) {
  int byte = (row << 10) + (col << 1);
  byte ^= (row & 7) << 4;
  return (u16*)((char*)tls + byte);
}

__global__ __launch_bounds__(512) void k6_mfma(const float* __restrict__ h,
    const u16* __restrict__ hb,
    const u16* __restrict__ w1t, const u16* __restrict__ w2t,
    const float* __restrict__ b1, const float* __restrict__ b2,
    const float* __restrict__ wn2, float* __restrict__ out)
{
  __shared__ u16 tls[32 * 512];
  int tid = threadIdx.x;
  int w = tid >> 6, lane = tid & 63;
  int quad = lane >> 4, l16 = lane & 15;
  int row0 = blockIdx.x * 32;
  int ko = quad * 8;

  // ---- GEMM1: f = gelu(h @ W1 + b1); wave w covers cols [w*64, w*64+64) ----
  f32x4v acc1[2][4];
#pragma unroll
  for (int mt = 0; mt < 2; ++mt)
#pragma unroll
    for (int nt = 0; nt < 4; ++nt) acc1[mt][nt] = (f32x4v){0.f, 0.f, 0.f, 0.f};
#pragma unroll
  for (int ks = 0; ks < 4; ++ks) {
    int k0 = ks * 32 + ko;
    s16x8 a[2];
#pragma unroll
    for (int mt = 0; mt < 2; ++mt) {
      int row = row0 + mt * 16 + l16; if (row >= NN) row = NN - 1;
      a[mt] = *(const s16x8*)(hb + row * 128 + k0);
    }
#pragma unroll
    for (int nt = 0; nt < 4; ++nt) {
      int col = w * 64 + nt * 16 + l16;
      s16x8 b = *(const s16x8*)(w1t + col * 128 + k0);
      acc1[0][nt] = mfma16(a[0], b, acc1[0][nt]);
      acc1[1][nt] = mfma16(a[1], b, acc1[1][nt]);
    }
  }
#pragma unroll
  for (int nt = 0; nt < 4; ++nt) {
    int col = w * 64 + nt * 16 + l16;
    float bb = b1[col];
#pragma unroll
    for (int mt = 0; mt < 2; ++mt)
#pragma unroll
      for (int r = 0; r < 4; ++r) {
        float t = gelu_fast(acc1[mt][nt][r] + bb);
        *tls_addr(tls, mt * 16 + quad * 4 + r, col) = f2b(t);
      }
  }
  __syncthreads();

  // ---- GEMM2: f @ W2; wave w covers cols [w*16, w*16+16) ----
  f32x4v acc2[2];
  acc2[0] = (f32x4v){0.f, 0.f, 0.f, 0.f};
  acc2[1] = (f32x4v){0.f, 0.f, 0.f, 0.f};
  int col = w * 16 + l16;
  const u16* bptr = w2t + col * 512;
#pragma unroll
  for (int ks = 0; ks < 16; ++ks) {
    int k0 = ks * 32 + ko;
    s16x8 a2[2];
#pragma unroll
    for (int mt = 0; mt < 2; ++mt)
      a2[mt] = *(const s16x8*)tls_addr(tls, mt * 16 + l16, k0);
    s16x8 b = *(const s16x8*)(bptr + k0);
    acc2[0] = mfma16(a2[0], b, acc2[0]);
    acc2[1] = mfma16(a2[1], b, acc2[1]);
  }

  // ---- epilogue: residual + bias, rmsnorm2 across 128 cols (8 waves) ----
  float bb2 = b2[col], wn = wn2[col];
  float ov[2][4];
#pragma unroll
  for (int mt = 0; mt < 2; ++mt)
#pragma unroll
    for (int r = 0; r < 4; ++r) {
      int row = row0 + mt * 16 + quad * 4 + r;
      int rowc = row < NN ? row : NN - 1;
      ov[mt][r] = h[rowc * 128 + col] + acc2[mt][r] + bb2;
    }
  __syncthreads();                         // tls reads done; reuse as red[8][32]
  float (*red)[32] = (float (*)[32])(void*)tls;
#pragma unroll
  for (int mt = 0; mt < 2; ++mt)
#pragma unroll
    for (int r = 0; r < 4; ++r) {
      float q = ov[mt][r] * ov[mt][r];
      q += __shfl_xor(q, 1); q += __shfl_xor(q, 2);
      q += __shfl_xor(q, 4); q += __shfl_xor(q, 8);
      if (l16 == 0) red[w][mt * 16 + quad * 4 + r] = q;
    }
  __syncthreads();
#pragma unroll
  for (int mt = 0; mt < 2; ++mt)
#pragma unroll
    for (int r = 0; r < 4; ++r) {
      int rl = mt * 16 + quad * 4 + r;
      float tot = ((red[0][rl] + red[1][rl]) + (red[2][rl] + red[3][rl]))
                + ((red[4][rl] + red[5][rl]) + (red[6][rl] + red[7][rl]));
      float rr = rsqrtf(tot * (1.f / 128.f) + RMS_EPS);
      int row = row0 + rl;
      if (row < NN) out[row * 128 + col] = ov[mt][r] * rr * wn;
    }
}

// ---------------- launch ----------------
extern "C" void kernel_launch(void* const* d_in, const int* in_sizes, int n_in,
                              void* d_out, int out_size, void* d_ws, size_t ws_size,
                              hipStream_t stream) {
  const float* x   = (const float*)d_in[0];
  const int*   ei  = (const int*)d_in[1];
  const float* ea  = (const float*)d_in[2];
  const float* Wl  = (const float*)d_in[3];
  const float* bl  = (const float*)d_in[4];
  const float* Wr  = (const float*)d_in[5];
  const float* br  = (const float*)d_in[6];
  const float* We  = (const float*)d_in[7];
  const float* att = (const float*)d_in[8];
  const float* bg  = (const float*)d_in[9];
  const float* wn1 = (const float*)d_in[10];
  const float* wn2 = (const float*)d_in[11];
  const float* W1  = (const float*)d_in[12];
  const float* b1  = (const float*)d_in[13];
  const float* W2  = (const float*)d_in[14];
  const float* b2  = (const float*)d_in[15];

  float* wsf = (float*)d_ws;
  int*   wsi = (int*)d_ws;

  float* gat  = wsf + OFF_GAT;
  u16* xlb    = (u16*)(wsf + OFF_XLB);
  u16* xrb    = (u16*)(wsf + OFF_XRB);
  int2* se    = (int2*)(wsf + OFF_SE);
  int* cnt    = wsi + OFF_CNT;
  int* pos    = wsi + OFF_CNT;   // alias: scan rebuilds in-place as cursors
  int* offs   = wsi + OFF_OFS;
  float* hbuf = wsf + OFF_H;     // aliases xlb+xrb (dead after k2)
  u16* hb     = (u16*)(wsf + OFF_HB);  // aliases se/cnt/offs (dead after k2)
  u16* wlrt   = (u16*)(wsf + OFF_WLRT);
  u16* w1t    = (u16*)(wsf + OFF_W1T);
  u16* w2t    = (u16*)(wsf + OFF_W2T);

  // fused prep (zero hist + weight transposes)
  k_prep<<<256, 256, 0, stream>>>(Wl, Wr, W1, W2, cnt, wlrt, w1t, w2t);

  // CSR structure
  k_hist<<<(EE + 255) / 256, 256, 0, stream>>>(ei, cnt);
  k_scan<<<1, 1024, 0, stream>>>(cnt, offs, pos);
  k_permute<<<(EE + 255) / 256, 256, 0, stream>>>(ei, pos, se);

  // node transforms (MFMA) -> bf16
  k1_mfma<<<(NN + 31) / 32, 256, 0, stream>>>(x, wlrt, bl, br, xlb, xrb);

  // fused logits + batched online softmax + weighted accumulation
  k2_attn<<<2048, 256, 0, stream>>>(offs, se, ea, att, We, xlb, xrb, gat);

  // norm1 (fp32 h for residual + bf16 hb for k6 A-operand)
  k5_norm1<<<NN / 4, 256, 0, stream>>>(x, gat, bg, wn1, hbuf, hb);

  // fused FFN (MFMA) + residual + norm2
  k6_mfma<<<(NN + 31) / 32, 512, 0, stream>>>(hbuf, hb, w1t, w2t, b1, b2, wn2, (float*)d_out);
}